// Round 7
// baseline (270.132 us; speedup 1.0000x reference)
//
#include <hip/hip_runtime.h>
#include <hip/hip_bf16.h>
#include <math.h>

#define S_LEN  2048
#define NBATCH 2
#define DMODEL 1024
#define NHEADS 16
#define HDIM   64
#define MROWS  (S_LEN*NBATCH)   // 4096
#define NBH    (NBATCH*NHEADS)  // 32

typedef __attribute__((ext_vector_type(8))) short          bf16x8;
typedef __attribute__((ext_vector_type(4))) float          f32x4;
typedef __attribute__((ext_vector_type(8))) unsigned short u16x8;

__device__ __forceinline__ unsigned short f2bf(float x) {
    union { __hip_bfloat16 h; unsigned short u; } c;
    c.h = __float2bfloat16(x);
    return c.u;
}
__device__ __forceinline__ unsigned int pk2(float a, float b) {
    return (unsigned int)f2bf(a) | ((unsigned int)f2bf(b) << 16);
}

// ===================== fp32 -> bf16 convert (7 arrays in one launch) =====================
__global__ __launch_bounds__(256)
void cvt7(const float* __restrict__ s0, const float* __restrict__ s1,
          const float* __restrict__ s2, const float* __restrict__ s3,
          const float* __restrict__ s4, const float* __restrict__ s5,
          const float* __restrict__ s6,
          unsigned short* __restrict__ d0, unsigned short* __restrict__ d1,
          unsigned short* __restrict__ d2, unsigned short* __restrict__ d3,
          unsigned short* __restrict__ d4, unsigned short* __restrict__ d5,
          unsigned short* __restrict__ d6)
{
    const float* s; unsigned short* d; int n;
    switch (blockIdx.y) {
        case 0: s = s0; d = d0; n = MROWS*DMODEL;  break;
        case 1: s = s1; d = d1; n = MROWS*DMODEL;  break;
        case 2: s = s2; d = d2; n = MROWS*DMODEL;  break;
        case 3: s = s3; d = d3; n = DMODEL*DMODEL; break;
        case 4: s = s4; d = d4; n = DMODEL*DMODEL; break;
        case 5: s = s5; d = d5; n = DMODEL*DMODEL; break;
        default: s = s6; d = d6; n = DMODEL*DMODEL; break;
    }
    int i = (blockIdx.x*256 + threadIdx.x) * 8;
    if (i >= n) return;
    float4 a = *(const float4*)(s + i);
    float4 b = *(const float4*)(s + i + 4);
    u16x8 o;
    o[0] = f2bf(a.x); o[1] = f2bf(a.y); o[2] = f2bf(a.z); o[3] = f2bf(a.w);
    o[4] = f2bf(b.x); o[5] = f2bf(b.y); o[6] = f2bf(b.z); o[7] = f2bf(b.w);
    *(u16x8*)(d + i) = o;
}

// ===================== bf16 MFMA GEMM: C = A[M,K]bf16 @ W[N,K]bf16^T + bias =====================
// MODE 0: fp32 C row-major [M, DMODEL]
// MODE 1: bf16 scatter to [B,H,S,HDIM], value scaled by `scale` (Q gets 0.125)
// MODE 2: bf16 TRANSPOSED scatter to [B,H,HDIM,S] via LDS tile (coalesced 16B stores)
#define GBM 128
#define GBN 128
#define GBK 32

template<int MODE>
__device__ __forceinline__ void gemm_bf16_core(
    const unsigned short* __restrict__ A,
    const unsigned short* __restrict__ W,
    const float* __restrict__ bias,
    float* __restrict__ Cf, unsigned short* __restrict__ Cb,
    float scale)
{
    __shared__ __align__(16) unsigned short As[GBM*GBK];
    __shared__ __align__(16) unsigned short Bs[GBN*GBK];

    const int tid = threadIdx.x;
    const int l   = tid & 63;
    const int w   = tid >> 6;
    const int m0  = blockIdx.y * GBM;
    const int n0  = blockIdx.x * GBN;
    const int wm  = (w >> 1) * 64;
    const int wn  = (w & 1) * 64;

    f32x4 acc[4][4];
    #pragma unroll
    for (int i = 0; i < 4; ++i)
        #pragma unroll
        for (int j = 0; j < 4; ++j)
            acc[i][j] = (f32x4){0.f, 0.f, 0.f, 0.f};

    const int srow = l >> 2;
    const int scol = (l & 3) * 8;

    for (int k0 = 0; k0 < DMODEL; k0 += GBK) {
        #pragma unroll
        for (int i = 0; i < 2; ++i) {
            int c = w*2 + i;
            const unsigned short* ga = A + (size_t)(m0 + c*16 + srow)*DMODEL + k0 + scol;
            const unsigned short* gb = W + (size_t)(n0 + c*16 + srow)*DMODEL + k0 + scol;
            __builtin_amdgcn_global_load_lds(
                (const __attribute__((address_space(1))) void*)ga,
                (__attribute__((address_space(3))) void*)(As + c*512), 16, 0, 0);
            __builtin_amdgcn_global_load_lds(
                (const __attribute__((address_space(1))) void*)gb,
                (__attribute__((address_space(3))) void*)(Bs + c*512), 16, 0, 0);
        }
        __syncthreads();

        bf16x8 af[4], bfr[4];
        #pragma unroll
        for (int f = 0; f < 4; ++f) {
            af[f]  = *(const bf16x8*)(As + (wm + f*16 + (l & 15))*GBK + (l >> 4)*8);
            bfr[f] = *(const bf16x8*)(Bs + (wn + f*16 + (l & 15))*GBK + (l >> 4)*8);
        }
        #pragma unroll
        for (int i = 0; i < 4; ++i)
            #pragma unroll
            for (int j = 0; j < 4; ++j)
                acc[i][j] = __builtin_amdgcn_mfma_f32_16x16x32_bf16(af[i], bfr[j], acc[i][j], 0, 0, 0);
        __syncthreads();
    }

    const int col_l = l & 15;
    const int row_l = (l >> 4) * 4;

    if constexpr (MODE == 2) {
        // --- transposed epilogue via LDS: emit [B,H,HDIM,S] with coalesced 16B stores ---
        __shared__ __align__(16) unsigned short tileS[64][136];  // stride 272 B
        #pragma unroll
        for (int ph = 0; ph < 2; ++ph) {
            __syncthreads();
            if ((w >> 1) == ph) {
                #pragma unroll
                for (int j = 0; j < 4; ++j) {
                    int c = wn + j*16 + col_l;
                    float bv = bias[n0 + c];
                    #pragma unroll
                    for (int i = 0; i < 4; ++i)
                        #pragma unroll
                        for (int r = 0; r < 4; ++r)
                            tileS[i*16 + row_l + r][c] = f2bf((acc[i][j][r] + bv) * scale);
                }
            }
            __syncthreads();
            const int sbase = (m0 + ph*64) >> 1;
            #pragma unroll
            for (int it = 0; it < 4; ++it) {
                int idx = it*256 + tid;         // 1024 chunks: c(128) x b(2) x sblk(4)
                int c    = idx >> 3;
                int bb   = (idx >> 2) & 1;
                int sl0  = (idx & 3) * 8;
                int hh   = (n0 + c) >> 6;
                int dd   = (n0 + c) & 63;
                u16x8 ov;
                #pragma unroll
                for (int k2 = 0; k2 < 8; ++k2)
                    ov[k2] = tileS[2*(sl0 + k2) + bb][c];
                *(u16x8*)(Cb + ((size_t)(bb*NHEADS + hh)*HDIM + dd)*S_LEN + sbase + sl0) = ov;
            }
        }
        return;
    }

    #pragma unroll
    for (int j = 0; j < 4; ++j) {
        int col = n0 + wn + j*16 + col_l;
        float bv = bias[col];
        #pragma unroll
        for (int i = 0; i < 4; ++i) {
            int mbase = m0 + wm + i*16 + row_l;
            #pragma unroll
            for (int r = 0; r < 4; ++r) {
                int m = mbase + r;
                float vout = (acc[i][j][r] + bv) * scale;
                if constexpr (MODE == 0) {
                    Cf[(size_t)m*DMODEL + col] = vout;
                } else {
                    int s = m >> 1, b = m & 1;       // A row = s*NBATCH + b
                    int h = col >> 6, d = col & 63;
                    Cb[((size_t)(b*NHEADS + h)*S_LEN + s)*HDIM + d] = f2bf(vout);
                }
            }
        }
    }
}

__global__ __launch_bounds__(256)
void gemm_qk(const unsigned short* __restrict__ qb, const unsigned short* __restrict__ kb,
             const unsigned short* __restrict__ Wqb, const float* __restrict__ bq,
             const unsigned short* __restrict__ Wkb, const float* __restrict__ bk,
             unsigned short* __restrict__ qp, unsigned short* __restrict__ kp)
{
    const int z = blockIdx.z;
    const unsigned short* A = (z==0) ? qb  : kb;
    const unsigned short* W = (z==0) ? Wqb : Wkb;
    const float* bias       = (z==0) ? bq  : bk;
    unsigned short* C       = (z==0) ? qp  : kp;
    float scale             = (z==0) ? 0.125f : 1.0f;   // fold 1/sqrt(dk) into Q
    gemm_bf16_core<1>(A, W, bias, nullptr, C, scale);
}

__global__ __launch_bounds__(256)
void gemm_vt(const unsigned short* __restrict__ vb, const unsigned short* __restrict__ Wvb,
             const float* __restrict__ bv, unsigned short* __restrict__ vt)
{
    gemm_bf16_core<2>(vb, Wvb, bv, nullptr, vt, 1.0f);
}

__global__ __launch_bounds__(256)
void gemm_out_bf16(const unsigned short* __restrict__ A, const unsigned short* __restrict__ W,
                   const float* __restrict__ bias, float* __restrict__ C)
{
    gemm_bf16_core<0>(A, W, bias, C, nullptr, 1.0f);
}

// ===================== Flash attention, bf16 MFMA, swapped QK^T, 2-phase pipeline ===========
// qp,kp: [BH][S][64] bf16 (Q pre-scaled). vt: [BH][64][S] bf16. x: [S*B][1024] bf16.
// 256 thr = 4 waves; QBLK=128 (32 q-rows/wave); KVBLK=64; K/V double-buffered.
// Per iter: ONE barrier (drains current-tile DMAs) -> issue next-tile global_load_lds ->
// compute (QK^T MFMA, in-lane softmax, P->per-wave LDS, PV MFMA). DMA overlaps compute.
#define QBLK  128
#define KVBLK 64
#define NT    (S_LEN/KVBLK)

__global__ __launch_bounds__(256)
void attn_mfma(const unsigned short* __restrict__ qp, const unsigned short* __restrict__ kp,
               const unsigned short* __restrict__ vt, unsigned short* __restrict__ x)
{
    __shared__ __align__(16) unsigned short Ks[2][KVBLK*HDIM];  // 2 x 8 KB
    __shared__ __align__(16) unsigned short Vs[2][KVBLK*HDIM];  // 2 x 8 KB
    __shared__ __align__(16) unsigned short Ps[4][32*KVBLK];    // 4 x 4 KB per-wave P

    const int tid = threadIdx.x;
    const int w   = tid >> 6;
    const int l   = tid & 63;
    const int g   = l >> 4;
    const int s16 = l & 15;
    const int q0  = blockIdx.x * QBLK;
    const int bh  = blockIdx.y;
    const int b   = bh >> 4;
    const int h   = bh & 15;
    const size_t base = (size_t)bh * S_LEN * HDIM;

    char* PsB = (char*)&Ps[w][0];

    // stage helper: 16 KB (K+V tile) via global_load_lds w=16, pre-swizzled source
#define STAGE(buf, kt_) do {                                                        \
    _Pragma("unroll")                                                               \
    for (int it_ = 0; it_ < 2; ++it_) {                                             \
        int idx_ = it_*256 + tid;                                                   \
        int row_ = idx_ >> 3;                                                       \
        int u_   = (idx_ & 7) ^ (row_ & 7);                                         \
        const unsigned short* gk_ = kp + base + (size_t)((kt_) + row_)*HDIM + u_*8; \
        __builtin_amdgcn_global_load_lds(                                           \
            (const __attribute__((address_space(1))) void*)gk_,                     \
            (__attribute__((address_space(3))) void*)(Ks[buf] + (it_*256 + w*64)*8),\
            16, 0, 0);                                                              \
        const unsigned short* gv_ = vt + base + (size_t)row_*S_LEN + (kt_) + u_*8;  \
        __builtin_amdgcn_global_load_lds(                                           \
            (const __attribute__((address_space(1))) void*)gv_,                     \
            (__attribute__((address_space(3))) void*)(Vs[buf] + (it_*256 + w*64)*8),\
            16, 0, 0);                                                              \
    }                                                                               \
} while (0)

    // Q fragments (B-operand): row = q0 + w*32 + ni*16 + s16, d = ks*32 + g*8
    bf16x8 qf[2][2];
    #pragma unroll
    for (int ni = 0; ni < 2; ++ni)
        #pragma unroll
        for (int ks = 0; ks < 2; ++ks) {
            int qrow = q0 + w*32 + ni*16 + s16;
            qf[ni][ks] = *(const bf16x8*)(qp + base + (size_t)qrow*HDIM + ks*32 + g*8);
        }

    f32x4 oacc[2][4];
    #pragma unroll
    for (int ni = 0; ni < 2; ++ni)
        #pragma unroll
        for (int nj = 0; nj < 4; ++nj)
            oacc[ni][nj] = (f32x4){0.f, 0.f, 0.f, 0.f};
    float run_m[2] = {-1e30f, -1e30f};
    float run_l[2] = {0.f, 0.f};

    STAGE(0, 0);

    for (int t = 0; t < NT; ++t) {
        const int cur = t & 1;
        __syncthreads();                 // drains current-tile DMAs; joins waves
        if (t + 1 < NT) STAGE(cur ^ 1, (t + 1)*KVBLK);

        const char* KsB = (const char*)Ks[cur];
        const char* VsB = (const char*)Vs[cur];

        // ---- QK^T (swapped): S^T[key][row] = sum_d K[key][d] * Q[row][d] ----
        f32x4 sacc[4][2];
        #pragma unroll
        for (int mi = 0; mi < 4; ++mi)
            #pragma unroll
            for (int ni = 0; ni < 2; ++ni)
                sacc[mi][ni] = (f32x4){0.f, 0.f, 0.f, 0.f};

        #pragma unroll
        for (int ks = 0; ks < 2; ++ks) {
            bf16x8 af[4];
            #pragma unroll
            for (int mi = 0; mi < 4; ++mi) {
                int key  = mi*16 + s16;
                int addr = ((key << 7) + (ks << 6) + (g << 4)) ^ ((key & 7) << 4);
                af[mi] = *(const bf16x8*)(KsB + addr);
            }
            #pragma unroll
            for (int mi = 0; mi < 4; ++mi)
                #pragma unroll
                for (int ni = 0; ni < 2; ++ni)
                    sacc[mi][ni] = __builtin_amdgcn_mfma_f32_16x16x32_bf16(
                        af[mi], qf[ni][ks], sacc[mi][ni], 0, 0, 0);
        }

        // ---- online softmax (lane owns 16 of 64 keys for row ni*16+s16) ----
        float al[2];
        #pragma unroll
        for (int ni = 0; ni < 2; ++ni) {
            float tm = -1e30f;
            #pragma unroll
            for (int mi = 0; mi < 4; ++mi)
                #pragma unroll
                for (int r = 0; r < 4; ++r)
                    tm = fmaxf(tm, sacc[mi][ni][r]);
            tm = fmaxf(tm, __shfl_xor(tm, 16));
            tm = fmaxf(tm, __shfl_xor(tm, 32));
            float mn = fmaxf(run_m[ni], tm);
            al[ni] = __expf(run_m[ni] - mn);
            float ps = 0.f;
            int row = ni*16 + s16;
            #pragma unroll
            for (int mi = 0; mi < 4; ++mi) {
                float p0 = __expf(sacc[mi][ni][0] - mn);
                float p1 = __expf(sacc[mi][ni][1] - mn);
                float p2 = __expf(sacc[mi][ni][2] - mn);
                float p3 = __expf(sacc[mi][ni][3] - mn);
                ps += (p0 + p1) + (p2 + p3);
                uint2 wv; wv.x = pk2(p0, p1); wv.y = pk2(p2, p3);
                int addr = ((row << 7) + (mi << 5) + (g << 3)) ^ ((row & 7) << 4);
                *(uint2*)(PsB + addr) = wv;
            }
            ps += __shfl_xor(ps, 16);
            ps += __shfl_xor(ps, 32);
            run_l[ni] = run_l[ni]*al[ni] + ps;
            run_m[ni] = mn;
        }

        // ---- rescale O ----
        float alo[2][4];
        #pragma unroll
        for (int ni = 0; ni < 2; ++ni)
            #pragma unroll
            for (int r = 0; r < 4; ++r)
                alo[ni][r] = __shfl(al[ni], 20*g + r);
        #pragma unroll
        for (int ni = 0; ni < 2; ++ni)
            #pragma unroll
            for (int nj = 0; nj < 4; ++nj)
                #pragma unroll
                for (int r = 0; r < 4; ++r)
                    oacc[ni][nj][r] *= alo[ni][r];

        // ---- PV: O[row][d] += P[row][key] @ Vt[d][key] ----
        #pragma unroll
        for (int ks = 0; ks < 2; ++ks) {
            bf16x8 pa[2];
            #pragma unroll
            for (int ni = 0; ni < 2; ++ni) {
                int row  = ni*16 + s16;
                int addr = ((row << 7) + (ks << 6) + (g << 4)) ^ ((row & 7) << 4);
                pa[ni] = *(const bf16x8*)(PsB + addr);
            }
            bf16x8 bv[4];
            #pragma unroll
            for (int nj = 0; nj < 4; ++nj) {
                int d    = nj*16 + s16;
                int addr = ((d << 7) + (ks << 6) + (g << 4)) ^ ((d & 7) << 4);
                bv[nj] = *(const bf16x8*)(VsB + addr);
            }
            #pragma unroll
            for (int ni = 0; ni < 2; ++ni)
                #pragma unroll
                for (int nj = 0; nj < 4; ++nj)
                    oacc[ni][nj] = __builtin_amdgcn_mfma_f32_16x16x32_bf16(
                        pa[ni], bv[nj], oacc[ni][nj], 0, 0, 0);
        }
        // no trailing barrier: next iter's top barrier provides the join
    }
#undef STAGE

    // ---- finalize: O-row r' = ni*16+4g+r, divide by run_l[r'], emit bf16 [S*B][1024] ----
    #pragma unroll
    for (int ni = 0; ni < 2; ++ni) {
        #pragma unroll
        for (int r = 0; r < 4; ++r) {
            float rl  = __shfl(run_l[ni], 20*g + r);
            float inv = 1.f / rl;
            int row = q0 + w*32 + ni*16 + 4*g + r;
            #pragma unroll
            for (int nj = 0; nj < 4; ++nj) {
                int col = h*HDIM + nj*16 + s16;
                x[(size_t)(row*NBATCH + b)*DMODEL + col] = f2bf(oacc[ni][nj][r] * inv);
            }
        }
    }
}

// ===================== launch =====================
extern "C" void kernel_launch(void* const* d_in, const int* in_sizes, int n_in,
                              void* d_out, int out_size, void* d_ws, size_t ws_size,
                              hipStream_t stream)
{
    const float* query = (const float*)d_in[0];
    const float* key_i = (const float*)d_in[1];
    const float* value = (const float*)d_in[2];
    const float* Wq = (const float*)d_in[3];
    const float* bq = (const float*)d_in[4];
    const float* Wk = (const float*)d_in[5];
    const float* bk = (const float*)d_in[6];
    const float* Wv = (const float*)d_in[7];
    const float* bv = (const float*)d_in[8];
    const float* Wo = (const float*)d_in[9];
    const float* bo = (const float*)d_in[10];
    float* out = (float*)d_out;

    // workspace (MB offsets): qb 0, kb 8, vb 16, Wqb 24, Wkb 26, Wvb 28, Wob 30,
    // qp 32, kp 40, vt 48, xab 56  -> 64 MB total
    char* ws = (char*)d_ws;
    unsigned short* qb  = (unsigned short*)(ws);
    unsigned short* kb2 = (unsigned short*)(ws + (size_t) 8*1024*1024);
    unsigned short* vb  = (unsigned short*)(ws + (size_t)16*1024*1024);
    unsigned short* Wqb = (unsigned short*)(ws + (size_t)24*1024*1024);
    unsigned short* Wkb = (unsigned short*)(ws + (size_t)26*1024*1024);
    unsigned short* Wvb = (unsigned short*)(ws + (size_t)28*1024*1024);
    unsigned short* Wob = (unsigned short*)(ws + (size_t)30*1024*1024);
    unsigned short* qp  = (unsigned short*)(ws + (size_t)32*1024*1024);
    unsigned short* kp  = (unsigned short*)(ws + (size_t)40*1024*1024);
    unsigned short* vt  = (unsigned short*)(ws + (size_t)48*1024*1024);
    unsigned short* xab = (unsigned short*)(ws + (size_t)56*1024*1024);

    dim3 gCvt(MROWS*DMODEL/(256*8), 7);
    cvt7<<<gCvt, 256, 0, stream>>>(query, key_i, value, Wq, Wk, Wv, Wo,
                                   qb, kb2, vb, Wqb, Wkb, Wvb, Wob);

    dim3 gQK(DMODEL/GBN, MROWS/GBM, 2);
    gemm_qk<<<gQK, 256, 0, stream>>>(qb, kb2, Wqb, bq, Wkb, bk, qp, kp);

    dim3 gV(DMODEL/GBN, MROWS/GBM);
    gemm_vt<<<gV, 256, 0, stream>>>(vb, Wvb, bv, vt);

    dim3 gAttn(S_LEN/QBLK, NBH);           // (16, 32)
    attn_mfma<<<gAttn, 256, 0, stream>>>(qp, kp, vt, xab);

    dim3 gOut(DMODEL/GBN, MROWS/GBM, 1);
    gemm_out_bf16<<<gOut, 256, 0, stream>>>(xab, Wob, bo, out);
}

// Round 8
// 261.558 us; speedup vs baseline: 1.0328x; 1.0328x over previous
//
#include <hip/hip_runtime.h>
#include <hip/hip_bf16.h>
#include <math.h>

#define S_LEN  2048
#define NBATCH 2
#define DMODEL 1024
#define NHEADS 16
#define HDIM   64
#define MROWS  (S_LEN*NBATCH)   // 4096
#define NBH    (NBATCH*NHEADS)  // 32

// Q projection scale: (1/sqrt(64)) * log2(e)  -> scores land in log2 domain
#define QSCALE 0.1803368801111f
#define DEFER_THR 11.5f          // 8 * log2(e): bound on exp2(s - m_stale)

typedef __attribute__((ext_vector_type(8))) short          bf16x8;
typedef __attribute__((ext_vector_type(4))) float          f32x4;
typedef __attribute__((ext_vector_type(8))) unsigned short u16x8;

__device__ __forceinline__ unsigned short f2bf(float x) {
    union { __hip_bfloat16 h; unsigned short u; } c;
    c.h = __float2bfloat16(x);
    return c.u;
}
__device__ __forceinline__ unsigned int pk2(float a, float b) {
    return (unsigned int)f2bf(a) | ((unsigned int)f2bf(b) << 16);
}

// ===================== fp32 -> bf16 convert (7 arrays in one launch) =====================
__global__ __launch_bounds__(256)
void cvt7(const float* __restrict__ s0, const float* __restrict__ s1,
          const float* __restrict__ s2, const float* __restrict__ s3,
          const float* __restrict__ s4, const float* __restrict__ s5,
          const float* __restrict__ s6,
          unsigned short* __restrict__ d0, unsigned short* __restrict__ d1,
          unsigned short* __restrict__ d2, unsigned short* __restrict__ d3,
          unsigned short* __restrict__ d4, unsigned short* __restrict__ d5,
          unsigned short* __restrict__ d6)
{
    const float* s; unsigned short* d; int n;
    switch (blockIdx.y) {
        case 0: s = s0; d = d0; n = MROWS*DMODEL;  break;
        case 1: s = s1; d = d1; n = MROWS*DMODEL;  break;
        case 2: s = s2; d = d2; n = MROWS*DMODEL;  break;
        case 3: s = s3; d = d3; n = DMODEL*DMODEL; break;
        case 4: s = s4; d = d4; n = DMODEL*DMODEL; break;
        case 5: s = s5; d = d5; n = DMODEL*DMODEL; break;
        default: s = s6; d = d6; n = DMODEL*DMODEL; break;
    }
    int i = (blockIdx.x*256 + threadIdx.x) * 8;
    if (i >= n) return;
    float4 a = *(const float4*)(s + i);
    float4 b = *(const float4*)(s + i + 4);
    u16x8 o;
    o[0] = f2bf(a.x); o[1] = f2bf(a.y); o[2] = f2bf(a.z); o[3] = f2bf(a.w);
    o[4] = f2bf(b.x); o[5] = f2bf(b.y); o[6] = f2bf(b.z); o[7] = f2bf(b.w);
    *(u16x8*)(d + i) = o;
}

// ===================== bf16 MFMA GEMM core: C = A[M,K] @ W[N,K]^T + bias ===================
// mode 0: fp32 C row-major [M, DMODEL]
// mode 1: bf16 scatter to [B,H,S,HDIM], scaled (Q gets QSCALE)
// mode 2: bf16 TRANSPOSED scatter to [B,H,HDIM,S] via LDS tile (TRANS instantiations only)
#define GBM 128
#define GBK 32

template<int BN_T, bool TRANS>
__device__ __forceinline__ void gemm_core(
    const unsigned short* __restrict__ A,
    const unsigned short* __restrict__ W,
    const float* __restrict__ bias,
    float* __restrict__ Cf, unsigned short* __restrict__ Cb,
    int mode, float scale)
{
    constexpr int FN  = BN_T / 32;   // B fragments per wave
    constexpr int BCW = BN_T / 64;   // B wave-chunks (1 KB) per wave
    __shared__ __align__(16) unsigned short As[GBM*GBK];
    __shared__ __align__(16) unsigned short Bs[BN_T*GBK];

    const int tid = threadIdx.x;
    const int l   = tid & 63;
    const int w   = tid >> 6;
    const int m0  = blockIdx.y * GBM;
    const int n0  = blockIdx.x * BN_T;
    const int wm  = (w >> 1) * 64;
    const int wn  = (w & 1) * (BN_T/2);

    f32x4 acc[4][FN];
    #pragma unroll
    for (int i = 0; i < 4; ++i)
        #pragma unroll
        for (int j = 0; j < FN; ++j)
            acc[i][j] = (f32x4){0.f, 0.f, 0.f, 0.f};

    const int srow = l >> 2;
    const int scol = (l & 3) * 8;

    for (int k0 = 0; k0 < DMODEL; k0 += GBK) {
        #pragma unroll
        for (int i = 0; i < 2; ++i) {
            int c = w*2 + i;
            const unsigned short* ga = A + (size_t)(m0 + c*16 + srow)*DMODEL + k0 + scol;
            __builtin_amdgcn_global_load_lds(
                (const __attribute__((address_space(1))) void*)ga,
                (__attribute__((address_space(3))) void*)(As + c*512), 16, 0, 0);
        }
        #pragma unroll
        for (int i = 0; i < BCW; ++i) {
            int c = w*BCW + i;
            const unsigned short* gb = W + (size_t)(n0 + c*16 + srow)*DMODEL + k0 + scol;
            __builtin_amdgcn_global_load_lds(
                (const __attribute__((address_space(1))) void*)gb,
                (__attribute__((address_space(3))) void*)(Bs + c*512), 16, 0, 0);
        }
        __syncthreads();

        bf16x8 af[4], bfr[FN];
        #pragma unroll
        for (int f = 0; f < 4; ++f)
            af[f]  = *(const bf16x8*)(As + (wm + f*16 + (l & 15))*GBK + (l >> 4)*8);
        #pragma unroll
        for (int f = 0; f < FN; ++f)
            bfr[f] = *(const bf16x8*)(Bs + (wn + f*16 + (l & 15))*GBK + (l >> 4)*8);
        #pragma unroll
        for (int i = 0; i < 4; ++i)
            #pragma unroll
            for (int j = 0; j < FN; ++j)
                acc[i][j] = __builtin_amdgcn_mfma_f32_16x16x32_bf16(af[i], bfr[j], acc[i][j], 0, 0, 0);
        __syncthreads();
    }

    const int col_l = l & 15;
    const int row_l = (l >> 4) * 4;

    if constexpr (TRANS) {
        if (mode == 2) {
            // transposed epilogue via LDS: emit [B,H,HDIM,S] with coalesced 16B stores
            __shared__ __align__(16) unsigned short tileS[64][136];
            #pragma unroll
            for (int ph = 0; ph < 2; ++ph) {
                __syncthreads();
                if ((w >> 1) == ph) {
                    #pragma unroll
                    for (int j = 0; j < FN; ++j) {
                        int c = wn + j*16 + col_l;
                        float bv = bias[n0 + c];
                        #pragma unroll
                        for (int i = 0; i < 4; ++i)
                            #pragma unroll
                            for (int r = 0; r < 4; ++r)
                                tileS[i*16 + row_l + r][c] = f2bf((acc[i][j][r] + bv) * scale);
                    }
                }
                __syncthreads();
                const int sbase = (m0 + ph*64) >> 1;
                #pragma unroll
                for (int it = 0; it < 4; ++it) {
                    int idx = it*256 + tid;
                    int c    = idx >> 3;
                    int bb   = (idx >> 2) & 1;
                    int sl0  = (idx & 3) * 8;
                    int hh   = (n0 + c) >> 6;
                    int dd   = (n0 + c) & 63;
                    u16x8 ov;
                    #pragma unroll
                    for (int k2 = 0; k2 < 8; ++k2)
                        ov[k2] = tileS[2*(sl0 + k2) + bb][c];
                    *(u16x8*)(Cb + ((size_t)(bb*NHEADS + hh)*HDIM + dd)*S_LEN + sbase + sl0) = ov;
                }
            }
            return;
        }
    }

    #pragma unroll
    for (int j = 0; j < FN; ++j) {
        int col = n0 + wn + j*16 + col_l;
        float bv = bias[col];
        #pragma unroll
        for (int i = 0; i < 4; ++i) {
            int mbase = m0 + wm + i*16 + row_l;
            #pragma unroll
            for (int r = 0; r < 4; ++r) {
                int m = mbase + r;
                float vout = (acc[i][j][r] + bv) * scale;
                if (mode == 0) {
                    Cf[(size_t)m*DMODEL + col] = vout;
                } else {
                    int s = m >> 1, b = m & 1;       // A row = s*NBATCH + b
                    int h = col >> 6, d = col & 63;
                    Cb[((size_t)(b*NHEADS + h)*S_LEN + s)*HDIM + d] = f2bf(vout);
                }
            }
        }
    }
}

// merged QKV: grid (8, 32, 3) = 768 blocks -> 3 blocks/CU concurrent
__global__ __launch_bounds__(256)
void gemm_qkv(const unsigned short* __restrict__ qb, const unsigned short* __restrict__ kb,
              const unsigned short* __restrict__ vb,
              const unsigned short* __restrict__ Wqb, const float* __restrict__ bq,
              const unsigned short* __restrict__ Wkb, const float* __restrict__ bk,
              const unsigned short* __restrict__ Wvb, const float* __restrict__ bv,
              unsigned short* __restrict__ qp, unsigned short* __restrict__ kp,
              unsigned short* __restrict__ vt)
{
    const int z = blockIdx.z;
    const unsigned short* A = (z==0) ? qb  : (z==1) ? kb  : vb;
    const unsigned short* W = (z==0) ? Wqb : (z==1) ? Wkb : Wvb;
    const float* bias       = (z==0) ? bq  : (z==1) ? bk  : bv;
    unsigned short* C       = (z==0) ? qp  : (z==1) ? kp  : vt;
    int   mode  = (z==2) ? 2 : 1;
    float scale = (z==0) ? QSCALE : 1.0f;
    gemm_core<128, true>(A, W, bias, nullptr, C, mode, scale);
}

// out-projection: 128x64 tile -> grid (16, 32) = 512 blocks -> 2 blocks/CU
__global__ __launch_bounds__(256)
void gemm_out(const unsigned short* __restrict__ A, const unsigned short* __restrict__ W,
              const float* __restrict__ bias, float* __restrict__ C)
{
    gemm_core<64, false>(A, W, bias, C, nullptr, 0, 1.0f);
}

// ===================== Flash attention: 8 waves, exp2 domain, defer-max =====================
// qp,kp: [BH][S][64] bf16 (Q pre-scaled by QSCALE -> scores in log2 domain).
// vt: [BH][64][S] bf16. x: [S*B][1024] bf16.
// 512 thr = 8 waves; wave owns 16 q-rows; KVBLK=64; K/V double-buffered, 1 barrier/iter.
#define QBLK  128
#define KVBLK 64
#define NT    (S_LEN/KVBLK)

__global__ __launch_bounds__(512)
void attn_mfma(const unsigned short* __restrict__ qp, const unsigned short* __restrict__ kp,
               const unsigned short* __restrict__ vt, unsigned short* __restrict__ x)
{
    __shared__ __align__(16) unsigned short Ks[2][KVBLK*HDIM];  // 2 x 8 KB
    __shared__ __align__(16) unsigned short Vs[2][KVBLK*HDIM];  // 2 x 8 KB
    __shared__ __align__(16) unsigned short Ps[8][16*KVBLK];    // 8 x 2 KB per-wave P

    const int tid = threadIdx.x;
    const int w   = tid >> 6;      // 0..7
    const int l   = tid & 63;
    const int g   = l >> 4;
    const int s16 = l & 15;
    const int q0  = blockIdx.x * QBLK;
    const int bh  = blockIdx.y;
    const int b   = bh >> 4;
    const int h   = bh & 15;
    const size_t base = (size_t)bh * S_LEN * HDIM;

    char* PsB = (char*)&Ps[w][0];

    // stage: 512 threads move 8 KB K + 8 KB V, one 16B chunk each; pre-swizzled source
#define STAGE(buf, kt_) do {                                                         \
    int row_ = tid >> 3;                                                             \
    int u_   = (tid & 7) ^ (row_ & 7);                                               \
    const unsigned short* gk_ = kp + base + (size_t)((kt_) + row_)*HDIM + u_*8;      \
    __builtin_amdgcn_global_load_lds(                                                \
        (const __attribute__((address_space(1))) void*)gk_,                          \
        (__attribute__((address_space(3))) void*)(Ks[buf] + w*512), 16, 0, 0);       \
    const unsigned short* gv_ = vt + base + (size_t)row_*S_LEN + (kt_) + u_*8;       \
    __builtin_amdgcn_global_load_lds(                                                \
        (const __attribute__((address_space(1))) void*)gv_,                          \
        (__attribute__((address_space(3))) void*)(Vs[buf] + w*512), 16, 0, 0);       \
} while (0)

    // Q fragments (B-operand): row = q0 + w*16 + s16, d = ks*32 + g*8
    bf16x8 qf[2];
    #pragma unroll
    for (int ks = 0; ks < 2; ++ks)
        qf[ks] = *(const bf16x8*)(qp + base + (size_t)(q0 + w*16 + s16)*HDIM + ks*32 + g*8);

    f32x4 oacc[4];
    #pragma unroll
    for (int nj = 0; nj < 4; ++nj) oacc[nj] = (f32x4){0.f, 0.f, 0.f, 0.f};
    float run_m = -1e30f;
    float run_l = 0.f;

    STAGE(0, 0);

    for (int t = 0; t < NT; ++t) {
        const int cur = t & 1;
        __syncthreads();                 // drains this tile's DMAs; joins waves
        if (t + 1 < NT) STAGE(cur ^ 1, (t + 1)*KVBLK);

        const char* KsB = (const char*)Ks[cur];
        const char* VsB = (const char*)Vs[cur];

        // ---- QK^T (swapped): lane holds S^T[key = mi*16+4g+reg][q-row = s16] ----
        f32x4 sacc[4];
        #pragma unroll
        for (int mi = 0; mi < 4; ++mi) sacc[mi] = (f32x4){0.f, 0.f, 0.f, 0.f};
        #pragma unroll
        for (int ks = 0; ks < 2; ++ks) {
            bf16x8 af[4];
            #pragma unroll
            for (int mi = 0; mi < 4; ++mi) {
                int key  = mi*16 + s16;
                int addr = ((key << 7) + (ks << 6) + (g << 4)) ^ ((key & 7) << 4);
                af[mi] = *(const bf16x8*)(KsB + addr);
            }
            #pragma unroll
            for (int mi = 0; mi < 4; ++mi)
                sacc[mi] = __builtin_amdgcn_mfma_f32_16x16x32_bf16(af[mi], qf[ks], sacc[mi], 0, 0, 0);
        }

        // ---- per-row max (max3-shaped tree, then cross-g shfl) ----
        float t0 = fmaxf(fmaxf(sacc[0][0], sacc[0][1]), sacc[0][2]);
        float t1 = fmaxf(fmaxf(sacc[0][3], sacc[1][0]), sacc[1][1]);
        float t2 = fmaxf(fmaxf(sacc[1][2], sacc[1][3]), sacc[2][0]);
        float t3 = fmaxf(fmaxf(sacc[2][1], sacc[2][2]), sacc[2][3]);
        float t4 = fmaxf(fmaxf(sacc[3][0], sacc[3][1]), sacc[3][2]);
        float tm = fmaxf(fmaxf(fmaxf(t0, t1), t2), fmaxf(fmaxf(t3, t4), sacc[3][3]));
        tm = fmaxf(tm, __shfl_xor(tm, 16));
        tm = fmaxf(tm, __shfl_xor(tm, 32));

        // ---- defer-max: skip rescale while max growth bounded (log2 domain) ----
        float mn, al;
        if (__all(tm <= run_m + DEFER_THR)) {
            mn = run_m; al = 1.0f;
        } else {
            mn = fmaxf(run_m, tm);
            al = exp2f(run_m - mn);
            run_m = mn;
            float alo[4];
            #pragma unroll
            for (int r = 0; r < 4; ++r) alo[r] = __shfl(al, 20*g + r);
            #pragma unroll
            for (int nj = 0; nj < 4; ++nj)
                #pragma unroll
                for (int r = 0; r < 4; ++r) oacc[nj][r] *= alo[r];
        }

        // ---- P = exp2(S - mn), row-sum, pack to per-wave LDS ----
        float ps = 0.f;
        #pragma unroll
        for (int mi = 0; mi < 4; ++mi) {
            float p0 = exp2f(sacc[mi][0] - mn);
            float p1 = exp2f(sacc[mi][1] - mn);
            float p2 = exp2f(sacc[mi][2] - mn);
            float p3 = exp2f(sacc[mi][3] - mn);
            ps += (p0 + p1) + (p2 + p3);
            uint2 wv; wv.x = pk2(p0, p1); wv.y = pk2(p2, p3);
            int addr = ((s16 << 7) + (mi << 5) + (g << 3)) ^ ((s16 & 7) << 4);
            *(uint2*)(PsB + addr) = wv;
        }
        ps += __shfl_xor(ps, 16);
        ps += __shfl_xor(ps, 32);
        run_l = run_l*al + ps;

        // ---- PV: O[q-row][d] += P[q-row][key] @ Vt[d][key] ----
        #pragma unroll
        for (int ks = 0; ks < 2; ++ks) {
            int paddr = ((s16 << 7) + (ks << 6) + (g << 4)) ^ ((s16 & 7) << 4);
            bf16x8 pa = *(const bf16x8*)(PsB + paddr);
            bf16x8 bv[4];
            #pragma unroll
            for (int nj = 0; nj < 4; ++nj) {
                int d    = nj*16 + s16;
                int addr = ((d << 7) + (ks << 6) + (g << 4)) ^ ((d & 7) << 4);
                bv[nj] = *(const bf16x8*)(VsB + addr);
            }
            #pragma unroll
            for (int nj = 0; nj < 4; ++nj)
                oacc[nj] = __builtin_amdgcn_mfma_f32_16x16x32_bf16(pa, bv[nj], oacc[nj], 0, 0, 0);
        }
        // next iter's top barrier provides the join
    }
#undef STAGE

    // ---- finalize: O-row = 4g+r, divide by run_l[row], emit bf16 [S*B][1024] ----
    #pragma unroll
    for (int r = 0; r < 4; ++r) {
        float rl  = __shfl(run_l, 20*g + r);
        float inv = 1.f / rl;
        int row = q0 + w*16 + 4*g + r;
        #pragma unroll
        for (int nj = 0; nj < 4; ++nj) {
            int col = h*HDIM + nj*16 + s16;
            x[(size_t)(row*NBATCH + b)*DMODEL + col] = f2bf(oacc[nj][r] * inv);
        }
    }
}

// ===================== launch =====================
extern "C" void kernel_launch(void* const* d_in, const int* in_sizes, int n_in,
                              void* d_out, int out_size, void* d_ws, size_t ws_size,
                              hipStream_t stream)
{
    const float* query = (const float*)d_in[0];
    const float* key_i = (const float*)d_in[1];
    const float* value = (const float*)d_in[2];
    const float* Wq = (const float*)d_in[3];
    const float* bq = (const float*)d_in[4];
    const float* Wk = (const float*)d_in[5];
    const float* bk = (const float*)d_in[6];
    const float* Wv = (const float*)d_in[7];
    const float* bv = (const float*)d_in[8];
    const float* Wo = (const float*)d_in[9];
    const float* bo = (const float*)d_in[10];
    float* out = (float*)d_out;

    // workspace (MB offsets): qb 0, kb 8, vb 16, Wqb 24, Wkb 26, Wvb 28, Wob 30,
    // qp 32, kp 40, vt 48, xab 56  -> 64 MB total
    char* ws = (char*)d_ws;
    unsigned short* qb  = (unsigned short*)(ws);
    unsigned short* kb2 = (unsigned short*)(ws + (size_t) 8*1024*1024);
    unsigned short* vb  = (unsigned short*)(ws + (size_t)16*1024*1024);
    unsigned short* Wqb = (unsigned short*)(ws + (size_t)24*1024*1024);
    unsigned short* Wkb = (unsigned short*)(ws + (size_t)26*1024*1024);
    unsigned short* Wvb = (unsigned short*)(ws + (size_t)28*1024*1024);
    unsigned short* Wob = (unsigned short*)(ws + (size_t)30*1024*1024);
    unsigned short* qp  = (unsigned short*)(ws + (size_t)32*1024*1024);
    unsigned short* kp  = (unsigned short*)(ws + (size_t)40*1024*1024);
    unsigned short* vt  = (unsigned short*)(ws + (size_t)48*1024*1024);
    unsigned short* xab = (unsigned short*)(ws + (size_t)56*1024*1024);

    dim3 gCvt(MROWS*DMODEL/(256*8), 7);
    cvt7<<<gCvt, 256, 0, stream>>>(query, key_i, value, Wq, Wk, Wv, Wo,
                                   qb, kb2, vb, Wqb, Wkb, Wvb, Wob);

    dim3 gQKV(DMODEL/128, MROWS/GBM, 3);   // (8, 32, 3) = 768 blocks, 3/CU
    gemm_qkv<<<gQKV, 256, 0, stream>>>(qb, kb2, vb,
                                       Wqb, bq, Wkb, bk, Wvb, bv,
                                       qp, kp, vt);

    dim3 gAttn(S_LEN/QBLK, NBH);           // (16, 32) = 512 blocks x 512 thr
    attn_mfma<<<gAttn, 512, 0, stream>>>(qp, kp, vt, xab);

    dim3 gOut(DMODEL/64, MROWS/GBM);       // (16, 32) = 512 blocks, 2/CU
    gemm_out<<<gOut, 256, 0, stream>>>(xab, Wob, bo, out);
}

// Round 9
// 253.204 us; speedup vs baseline: 1.0669x; 1.0330x over previous
//
#include <hip/hip_runtime.h>
#include <hip/hip_bf16.h>
#include <math.h>

#define S_LEN  2048
#define NBATCH 2
#define DMODEL 1024
#define NHEADS 16
#define HDIM   64
#define MROWS  (S_LEN*NBATCH)   // 4096
#define NBH    (NBATCH*NHEADS)  // 32

// Q projection scale: (1/sqrt(64)) * log2(e)  -> scores land in log2 domain
#define QSCALE 0.1803368801111f
#define DEFER_THR 11.5f          // 8 * log2(e): bound on exp2(s - m_stale)

typedef __attribute__((ext_vector_type(8))) short          bf16x8;
typedef __attribute__((ext_vector_type(4))) float          f32x4;
typedef __attribute__((ext_vector_type(8))) unsigned short u16x8;

__device__ __forceinline__ unsigned short f2bf(float x) {
    union { __hip_bfloat16 h; unsigned short u; } c;
    c.h = __float2bfloat16(x);
    return c.u;
}
// one VOP3 instruction packs two f32 -> two bf16 (RNE); no builtin on gfx950 (m240)
__device__ __forceinline__ unsigned int cvtpk_bf16(float lo, float hi) {
    unsigned int r;
    asm("v_cvt_pk_bf16_f32 %0, %1, %2" : "=v"(r) : "v"(lo), "v"(hi));
    return r;
}

// ===================== fp32 -> bf16 convert (7 arrays in one launch) =====================
__global__ __launch_bounds__(256)
void cvt7(const float* __restrict__ s0, const float* __restrict__ s1,
          const float* __restrict__ s2, const float* __restrict__ s3,
          const float* __restrict__ s4, const float* __restrict__ s5,
          const float* __restrict__ s6,
          unsigned short* __restrict__ d0, unsigned short* __restrict__ d1,
          unsigned short* __restrict__ d2, unsigned short* __restrict__ d3,
          unsigned short* __restrict__ d4, unsigned short* __restrict__ d5,
          unsigned short* __restrict__ d6)
{
    const float* s; unsigned short* d; int n;
    switch (blockIdx.y) {
        case 0: s = s0; d = d0; n = MROWS*DMODEL;  break;
        case 1: s = s1; d = d1; n = MROWS*DMODEL;  break;
        case 2: s = s2; d = d2; n = MROWS*DMODEL;  break;
        case 3: s = s3; d = d3; n = DMODEL*DMODEL; break;
        case 4: s = s4; d = d4; n = DMODEL*DMODEL; break;
        case 5: s = s5; d = d5; n = DMODEL*DMODEL; break;
        default: s = s6; d = d6; n = DMODEL*DMODEL; break;
    }
    int i = (blockIdx.x*256 + threadIdx.x) * 8;
    if (i >= n) return;
    float4 a = *(const float4*)(s + i);
    float4 b = *(const float4*)(s + i + 4);
    u16x8 o;
    o[0] = f2bf(a.x); o[1] = f2bf(a.y); o[2] = f2bf(a.z); o[3] = f2bf(a.w);
    o[4] = f2bf(b.x); o[5] = f2bf(b.y); o[6] = f2bf(b.z); o[7] = f2bf(b.w);
    *(u16x8*)(d + i) = o;
}

// ===================== bf16 MFMA GEMM core (FROZEN from round 8) ===================
#define GBM 128
#define GBK 32

template<int BN_T, bool TRANS>
__device__ __forceinline__ void gemm_core(
    const unsigned short* __restrict__ A,
    const unsigned short* __restrict__ W,
    const float* __restrict__ bias,
    float* __restrict__ Cf, unsigned short* __restrict__ Cb,
    int mode, float scale)
{
    constexpr int FN  = BN_T / 32;   // B fragments per wave
    constexpr int BCW = BN_T / 64;   // B wave-chunks (1 KB) per wave
    __shared__ __align__(16) unsigned short As[GBM*GBK];
    __shared__ __align__(16) unsigned short Bs[BN_T*GBK];

    const int tid = threadIdx.x;
    const int l   = tid & 63;
    const int w   = tid >> 6;
    const int m0  = blockIdx.y * GBM;
    const int n0  = blockIdx.x * BN_T;
    const int wm  = (w >> 1) * 64;
    const int wn  = (w & 1) * (BN_T/2);

    f32x4 acc[4][FN];
    #pragma unroll
    for (int i = 0; i < 4; ++i)
        #pragma unroll
        for (int j = 0; j < FN; ++j)
            acc[i][j] = (f32x4){0.f, 0.f, 0.f, 0.f};

    const int srow = l >> 2;
    const int scol = (l & 3) * 8;

    for (int k0 = 0; k0 < DMODEL; k0 += GBK) {
        #pragma unroll
        for (int i = 0; i < 2; ++i) {
            int c = w*2 + i;
            const unsigned short* ga = A + (size_t)(m0 + c*16 + srow)*DMODEL + k0 + scol;
            __builtin_amdgcn_global_load_lds(
                (const __attribute__((address_space(1))) void*)ga,
                (__attribute__((address_space(3))) void*)(As + c*512), 16, 0, 0);
        }
        #pragma unroll
        for (int i = 0; i < BCW; ++i) {
            int c = w*BCW + i;
            const unsigned short* gb = W + (size_t)(n0 + c*16 + srow)*DMODEL + k0 + scol;
            __builtin_amdgcn_global_load_lds(
                (const __attribute__((address_space(1))) void*)gb,
                (__attribute__((address_space(3))) void*)(Bs + c*512), 16, 0, 0);
        }
        __syncthreads();

        bf16x8 af[4], bfr[FN];
        #pragma unroll
        for (int f = 0; f < 4; ++f)
            af[f]  = *(const bf16x8*)(As + (wm + f*16 + (l & 15))*GBK + (l >> 4)*8);
        #pragma unroll
        for (int f = 0; f < FN; ++f)
            bfr[f] = *(const bf16x8*)(Bs + (wn + f*16 + (l & 15))*GBK + (l >> 4)*8);
        #pragma unroll
        for (int i = 0; i < 4; ++i)
            #pragma unroll
            for (int j = 0; j < FN; ++j)
                acc[i][j] = __builtin_amdgcn_mfma_f32_16x16x32_bf16(af[i], bfr[j], acc[i][j], 0, 0, 0);
        __syncthreads();
    }

    const int col_l = l & 15;
    const int row_l = (l >> 4) * 4;

    if constexpr (TRANS) {
        if (mode == 2) {
            __shared__ __align__(16) unsigned short tileS[64][136];
            #pragma unroll
            for (int ph = 0; ph < 2; ++ph) {
                __syncthreads();
                if ((w >> 1) == ph) {
                    #pragma unroll
                    for (int j = 0; j < FN; ++j) {
                        int c = wn + j*16 + col_l;
                        float bv = bias[n0 + c];
                        #pragma unroll
                        for (int i = 0; i < 4; ++i)
                            #pragma unroll
                            for (int r = 0; r < 4; ++r)
                                tileS[i*16 + row_l + r][c] = f2bf((acc[i][j][r] + bv) * scale);
                    }
                }
                __syncthreads();
                const int sbase = (m0 + ph*64) >> 1;
                #pragma unroll
                for (int it = 0; it < 4; ++it) {
                    int idx = it*256 + tid;
                    int c    = idx >> 3;
                    int bb   = (idx >> 2) & 1;
                    int sl0  = (idx & 3) * 8;
                    int hh   = (n0 + c) >> 6;
                    int dd   = (n0 + c) & 63;
                    u16x8 ov;
                    #pragma unroll
                    for (int k2 = 0; k2 < 8; ++k2)
                        ov[k2] = tileS[2*(sl0 + k2) + bb][c];
                    *(u16x8*)(Cb + ((size_t)(bb*NHEADS + hh)*HDIM + dd)*S_LEN + sbase + sl0) = ov;
                }
            }
            return;
        }
    }

    #pragma unroll
    for (int j = 0; j < FN; ++j) {
        int col = n0 + wn + j*16 + col_l;
        float bv = bias[col];
        #pragma unroll
        for (int i = 0; i < 4; ++i) {
            int mbase = m0 + wm + i*16 + row_l;
            #pragma unroll
            for (int r = 0; r < 4; ++r) {
                int m = mbase + r;
                float vout = (acc[i][j][r] + bv) * scale;
                if (mode == 0) {
                    Cf[(size_t)m*DMODEL + col] = vout;
                } else {
                    int s = m >> 1, b = m & 1;       // A row = s*NBATCH + b
                    int h = col >> 6, d = col & 63;
                    Cb[((size_t)(b*NHEADS + h)*S_LEN + s)*HDIM + d] = f2bf(vout);
                }
            }
        }
    }
}

__global__ __launch_bounds__(256)
void gemm_qkv(const unsigned short* __restrict__ qb, const unsigned short* __restrict__ kb,
              const unsigned short* __restrict__ vb,
              const unsigned short* __restrict__ Wqb, const float* __restrict__ bq,
              const unsigned short* __restrict__ Wkb, const float* __restrict__ bk,
              const unsigned short* __restrict__ Wvb, const float* __restrict__ bv,
              unsigned short* __restrict__ qp, unsigned short* __restrict__ kp,
              unsigned short* __restrict__ vt)
{
    const int z = blockIdx.z;
    const unsigned short* A = (z==0) ? qb  : (z==1) ? kb  : vb;
    const unsigned short* W = (z==0) ? Wqb : (z==1) ? Wkb : Wvb;
    const float* bias       = (z==0) ? bq  : (z==1) ? bk  : bv;
    unsigned short* C       = (z==0) ? qp  : (z==1) ? kp  : vt;
    int   mode  = (z==2) ? 2 : 1;
    float scale = (z==0) ? QSCALE : 1.0f;
    gemm_core<128, true>(A, W, bias, nullptr, C, mode, scale);
}

__global__ __launch_bounds__(256)
void gemm_out(const unsigned short* __restrict__ A, const unsigned short* __restrict__ W,
              const float* __restrict__ bias, float* __restrict__ C)
{
    gemm_core<64, false>(A, W, bias, C, nullptr, 0, 1.0f);
}

// ===================== Flash attention: instruction-diet version =====================
// qp,kp: [BH][S][64] bf16 (Q pre-scaled by QSCALE -> scores in log2 domain).
// vt: [BH][64][S] bf16. x: [S*B][1024] bf16.
// 512 thr = 8 waves; wave owns 16 q-rows; KVBLK=64; K/V double-buffered (static index).
// Steady-state loop: NO cross-lane ops (lane-local defer-max + per-lane partial l),
// cvt_pk for P packing, setprio around MFMA clusters, x2-unrolled buffers.
#define QBLK  128
#define KVBLK 64
#define NT    (S_LEN/KVBLK)

__global__ __launch_bounds__(512)
void attn_mfma(const unsigned short* __restrict__ qp, const unsigned short* __restrict__ kp,
               const unsigned short* __restrict__ vt, unsigned short* __restrict__ x)
{
    __shared__ __align__(16) unsigned short Ks[2][KVBLK*HDIM];  // 2 x 8 KB
    __shared__ __align__(16) unsigned short Vs[2][KVBLK*HDIM];  // 2 x 8 KB
    __shared__ __align__(16) unsigned short Ps[8][16*KVBLK];    // 8 x 2 KB per-wave P

    const int tid = threadIdx.x;
    const int w   = tid >> 6;      // 0..7
    const int l   = tid & 63;
    const int g   = l >> 4;
    const int s16 = l & 15;
    const int q0  = blockIdx.x * QBLK;
    const int bh  = blockIdx.y;
    const int b   = bh >> 4;
    const int h   = bh & 15;
    const size_t base = (size_t)bh * S_LEN * HDIM;

    char* PsB = (char*)&Ps[w][0];

    // stage: 512 threads move 8 KB K + 8 KB V, one 16B chunk each; pre-swizzled source
#define STAGE(buf_, kt_) do {                                                        \
    int row_ = tid >> 3;                                                             \
    int u_   = (tid & 7) ^ (row_ & 7);                                               \
    const unsigned short* gk_ = kp + base + (size_t)((kt_) + row_)*HDIM + u_*8;      \
    __builtin_amdgcn_global_load_lds(                                                \
        (const __attribute__((address_space(1))) void*)gk_,                          \
        (__attribute__((address_space(3))) void*)(Ks[buf_] + w*512), 16, 0, 0);      \
    const unsigned short* gv_ = vt + base + (size_t)row_*S_LEN + (kt_) + u_*8;       \
    __builtin_amdgcn_global_load_lds(                                                \
        (const __attribute__((address_space(1))) void*)gv_,                          \
        (__attribute__((address_space(3))) void*)(Vs[buf_] + w*512), 16, 0, 0);      \
} while (0)

    // one KV-tile iteration; buf_ is a LITERAL 0/1 -> static LDS addressing
#define ITER(buf_, t_) do {                                                          \
    __syncthreads();                                                                 \
    if ((t_) + 1 < NT) STAGE(buf_ ^ 1, ((t_) + 1)*KVBLK);                            \
    const char* KsB_ = (const char*)Ks[buf_];                                        \
    const char* VsB_ = (const char*)Vs[buf_];                                        \
    f32x4 sacc[4];                                                                   \
    _Pragma("unroll")                                                                \
    for (int mi = 0; mi < 4; ++mi) sacc[mi] = (f32x4){0.f, 0.f, 0.f, 0.f};           \
    __builtin_amdgcn_s_setprio(1);                                                   \
    _Pragma("unroll")                                                                \
    for (int ks = 0; ks < 2; ++ks) {                                                 \
        bf16x8 af[4];                                                                \
        _Pragma("unroll")                                                            \
        for (int mi = 0; mi < 4; ++mi) {                                             \
            int key  = mi*16 + s16;                                                  \
            int addr = ((key << 7) + (ks << 6) + (g << 4)) ^ ((key & 7) << 4);       \
            af[mi] = *(const bf16x8*)(KsB_ + addr);                                  \
        }                                                                            \
        _Pragma("unroll")                                                            \
        for (int mi = 0; mi < 4; ++mi)                                               \
            sacc[mi] = __builtin_amdgcn_mfma_f32_16x16x32_bf16(af[mi], qf[ks], sacc[mi], 0, 0, 0); \
    }                                                                                \
    __builtin_amdgcn_s_setprio(0);                                                   \
    /* lane-local max over this lane's 16 keys (max3-shaped) */                      \
    float t0_ = fmaxf(fmaxf(sacc[0][0], sacc[0][1]), sacc[0][2]);                    \
    float t1_ = fmaxf(fmaxf(sacc[0][3], sacc[1][0]), sacc[1][1]);                    \
    float t2_ = fmaxf(fmaxf(sacc[1][2], sacc[1][3]), sacc[2][0]);                    \
    float t3_ = fmaxf(fmaxf(sacc[2][1], sacc[2][2]), sacc[2][3]);                    \
    float t4_ = fmaxf(fmaxf(sacc[3][0], sacc[3][1]), sacc[3][2]);                    \
    float tm_ = fmaxf(fmaxf(fmaxf(t0_, t1_), t2_), fmaxf(fmaxf(t3_, t4_), sacc[3][3])); \
    float mn_;                                                                       \
    /* defer-max: __all over lane-local maxima == AND over row maxima (rows partition the wave) */ \
    if (__all(tm_ <= run_m + DEFER_THR)) {                                           \
        mn_ = run_m;                                                                 \
    } else {                                                                         \
        float tr_ = fmaxf(tm_, __shfl_xor(tm_, 16));                                 \
        tr_ = fmaxf(tr_, __shfl_xor(tr_, 32));                                       \
        mn_ = fmaxf(run_m, tr_);                                                     \
        float al_ = exp2f(run_m - mn_);                                              \
        run_m = mn_;                                                                 \
        part_l *= al_;                                                               \
        float a0_ = __shfl(al_, 20*g + 0), a1_ = __shfl(al_, 20*g + 1);              \
        float a2_ = __shfl(al_, 20*g + 2), a3_ = __shfl(al_, 20*g + 3);              \
        _Pragma("unroll")                                                            \
        for (int nj = 0; nj < 4; ++nj) {                                             \
            oacc[nj][0] *= a0_; oacc[nj][1] *= a1_;                                  \
            oacc[nj][2] *= a2_; oacc[nj][3] *= a3_;                                  \
        }                                                                            \
    }                                                                                \
    /* P = exp2(S - mn), per-lane partial sum, cvt_pk pack to per-wave LDS */        \
    float ps_ = 0.f;                                                                 \
    _Pragma("unroll")                                                                \
    for (int mi = 0; mi < 4; ++mi) {                                                 \
        float p0_ = exp2f(sacc[mi][0] - mn_);                                        \
        float p1_ = exp2f(sacc[mi][1] - mn_);                                        \
        float p2_ = exp2f(sacc[mi][2] - mn_);                                        \
        float p3_ = exp2f(sacc[mi][3] - mn_);                                        \
        ps_ += (p0_ + p1_) + (p2_ + p3_);                                            \
        uint2 wv_; wv_.x = cvtpk_bf16(p0_, p1_); wv_.y = cvtpk_bf16(p2_, p3_);       \
        int addr = ((s16 << 7) + (mi << 5) + (g << 3)) ^ ((s16 & 7) << 4);           \
        *(uint2*)(PsB + addr) = wv_;                                                 \
    }                                                                                \
    part_l += ps_;                                                                   \
    /* PV: O[q-row][d] += P[q-row][key] @ Vt[d][key] */                              \
    __builtin_amdgcn_s_setprio(1);                                                   \
    _Pragma("unroll")                                                                \
    for (int ks = 0; ks < 2; ++ks) {                                                 \
        int paddr = ((s16 << 7) + (ks << 6) + (g << 4)) ^ ((s16 & 7) << 4);          \
        bf16x8 pa = *(const bf16x8*)(PsB + paddr);                                   \
        _Pragma("unroll")                                                            \
        for (int nj = 0; nj < 4; ++nj) {                                             \
            int d    = nj*16 + s16;                                                  \
            int addr = ((d << 7) + (ks << 6) + (g << 4)) ^ ((d & 7) << 4);           \
            bf16x8 bv = *(const bf16x8*)(VsB_ + addr);                               \
            oacc[nj] = __builtin_amdgcn_mfma_f32_16x16x32_bf16(pa, bv, oacc[nj], 0, 0, 0); \
        }                                                                            \
    }                                                                                \
    __builtin_amdgcn_s_setprio(0);                                                   \
} while (0)

    // Q fragments (B-operand): row = q0 + w*16 + s16, d = ks*32 + g*8
    bf16x8 qf[2];
    #pragma unroll
    for (int ks = 0; ks < 2; ++ks)
        qf[ks] = *(const bf16x8*)(qp + base + (size_t)(q0 + w*16 + s16)*HDIM + ks*32 + g*8);

    f32x4 oacc[4];
    #pragma unroll
    for (int nj = 0; nj < 4; ++nj) oacc[nj] = (f32x4){0.f, 0.f, 0.f, 0.f};
    float run_m  = -1e30f;
    float part_l = 0.f;     // per-lane partial softmax denominator (16 keys/lane/iter)

    STAGE(0, 0);

    for (int t = 0; t < NT; t += 2) {
        ITER(0, t);
        ITER(1, t + 1);
    }
#undef ITER
#undef STAGE

    // ---- finalize: row denominator = sum of 4 g-lane partials; O-row = 4g+r ----
    float lt = part_l;
    lt += __shfl_xor(lt, 16);
    lt += __shfl_xor(lt, 32);
    #pragma unroll
    for (int r = 0; r < 4; ++r) {
        float rl  = __shfl(lt, 20*g + r);
        float inv = 1.f / rl;
        int row = q0 + w*16 + 4*g + r;
        #pragma unroll
        for (int nj = 0; nj < 4; ++nj) {
            int col = h*HDIM + nj*16 + s16;
            x[(size_t)(row*NBATCH + b)*DMODEL + col] = f2bf(oacc[nj][r] * inv);
        }
    }
}

// ===================== launch =====================
extern "C" void kernel_launch(void* const* d_in, const int* in_sizes, int n_in,
                              void* d_out, int out_size, void* d_ws, size_t ws_size,
                              hipStream_t stream)
{
    const float* query = (const float*)d_in[0];
    const float* key_i = (const float*)d_in[1];
    const float* value = (const float*)d_in[2];
    const float* Wq = (const float*)d_in[3];
    const float* bq = (const float*)d_in[4];
    const float* Wk = (const float*)d_in[5];
    const float* bk = (const float*)d_in[6];
    const float* Wv = (const float*)d_in[7];
    const float* bv = (const float*)d_in[8];
    const float* Wo = (const float*)d_in[9];
    const float* bo = (const float*)d_in[10];
    float* out = (float*)d_out;

    // workspace (MB offsets): qb 0, kb 8, vb 16, Wqb 24, Wkb 26, Wvb 28, Wob 30,
    // qp 32, kp 40, vt 48, xab 56  -> 64 MB total
    char* ws = (char*)d_ws;
    unsigned short* qb  = (unsigned short*)(ws);
    unsigned short* kb2 = (unsigned short*)(ws + (size_t) 8*1024*1024);
    unsigned short* vb  = (unsigned short*)(ws + (size_t)16*1024*1024);
    unsigned short* Wqb = (unsigned short*)(ws + (size_t)24*1024*1024);
    unsigned short* Wkb = (unsigned short*)(ws + (size_t)26*1024*1024);
    unsigned short* Wvb = (unsigned short*)(ws + (size_t)28*1024*1024);
    unsigned short* Wob = (unsigned short*)(ws + (size_t)30*1024*1024);
    unsigned short* qp  = (unsigned short*)(ws + (size_t)32*1024*1024);
    unsigned short* kp  = (unsigned short*)(ws + (size_t)40*1024*1024);
    unsigned short* vt  = (unsigned short*)(ws + (size_t)48*1024*1024);
    unsigned short* xab = (unsigned short*)(ws + (size_t)56*1024*1024);

    dim3 gCvt(MROWS*DMODEL/(256*8), 7);
    cvt7<<<gCvt, 256, 0, stream>>>(query, key_i, value, Wq, Wk, Wv, Wo,
                                   qb, kb2, vb, Wqb, Wkb, Wvb, Wob);

    dim3 gQKV(DMODEL/128, MROWS/GBM, 3);   // (8, 32, 3) = 768 blocks, 3/CU
    gemm_qkv<<<gQKV, 256, 0, stream>>>(qb, kb2, vb,
                                       Wqb, bq, Wkb, bk, Wvb, bv,
                                       qp, kp, vt);

    dim3 gAttn(S_LEN/QBLK, NBH);           // (16, 32) = 512 blocks x 512 thr
    attn_mfma<<<gAttn, 512, 0, stream>>>(qp, kp, vt, xab);

    dim3 gOut(DMODEL/64, MROWS/GBM);       // (16, 32) = 512 blocks, 2/CU
    gemm_out<<<gOut, 256, 0, stream>>>(xab, Wob, bo, out);
}